// Round 1
// baseline (160.589 us; speedup 1.0000x reference)
//
#include <hip/hip_runtime.h>
#include <math.h>

// QuGCN: batched 8-qubit statevector simulation.
// samples = x.T  -> sample b, amplitude s = x[s*4096 + b] / ||x[:,b]||
// wire q <-> state bit p = 7-q (wire 0 = MSB).
// One wave per sample; 4 complex amps per lane: s = (lane<<2) | r.

namespace {

constexpr int NSAMP  = 4096;   // IN_FEATURES (batch)
constexpr int NW_L   = 132;    // weights per layer
constexpr int LAYERS = 4;

// ---------- compile-time trig for the constant-angle controlled gates ----------
constexpr double PI_D   = 3.14159265358979323846264338327950288;
constexpr double TWO_PI = 6.28318530717958647692528676655900577;

constexpr double red_pm_pi(double x) {
  // x in [0, ~64): reduce to [-pi, pi]
  double k = x / TWO_PI;
  long long ki = (long long)k;
  double r = x - (double)ki * TWO_PI;
  if (r > PI_D) r -= TWO_PI;
  return r;
}
constexpr double csin(double x) {
  double r = red_pm_pi(x);
  double r2 = r * r;
  double term = r, sum = r;
  for (int n = 1; n <= 13; ++n) {
    term *= -r2 / (double)((2 * n) * (2 * n + 1));
    sum += term;
  }
  return sum;
}
constexpr double ccos(double x) {
  double r = red_pm_pi(x);
  double r2 = r * r;
  double term = 1.0, sum = 1.0;
  for (int n = 1; n <= 13; ++n) {
    term *= -r2 / (double)((2 * n - 1) * (2 * n));
    sum += term;
  }
  return sum;
}

struct Tbl28 { float c[28]; float s[28]; };
constexpr Tbl28 mk_tbl(int base) {
  Tbl28 t{};
  for (int i = 0; i < 28; ++i) {
    double a = 0.5 * (double)(base + i);   // half-angle; angle = base+i (the source quirk)
    t.c[i] = (float)ccos(a);
    t.s[i] = (float)csin(a);
  }
  return t;
}
constexpr Tbl28 T_CRY = mk_tbl(8);    // CRY angles 8..35
constexpr Tbl28 T_CRX = mk_tbl(52);   // CRX angles 52..79
constexpr Tbl28 T_CRZ = mk_tbl(96);   // CRZ angles 96..123

// PAIRS: (j, j+gap) for gap = 1..7, j = 0..7-gap-1  (control < target always)
constexpr int PC[28] = {0,1,2,3,4,5,6, 0,1,2,3,4,5, 0,1,2,3,4, 0,1,2,3, 0,1,2, 0,1, 0};
constexpr int PT[28] = {1,2,3,4,5,6,7, 2,3,4,5,6,7, 3,4,5,6,7, 4,5,6,7, 5,6,7, 6,7, 7};

// ---------- gate kernels on the register-resident state ----------
// ar/ai: 4 complex amps of this lane. q: wire. Bit p = 7-q.
// p >= 2: cross-lane (lane mask 1<<(p-2)); p < 2: intra-lane (r mask 1<<p).

__device__ __forceinline__ void ry_gate(float* ar, float* ai, int lane, int q,
                                        float c, float s) {
  const int p = 7 - q;
  if (p >= 2) {
    const int sh = p - 2;
    const int lm = 1 << sh;
    const float sg = ((lane >> sh) & 1) ? s : -s;  // bit0: new0=c*a0-s*a1 ; bit1: new1=s*a0+c*a1
#pragma unroll
    for (int r = 0; r < 4; ++r) {
      float pr = __shfl_xor(ar[r], lm, 64);
      float pi = __shfl_xor(ai[r], lm, 64);
      ar[r] = fmaf(sg, pr, c * ar[r]);
      ai[r] = fmaf(sg, pi, c * ai[r]);
    }
  } else {
    const int m = 1 << p;
#pragma unroll
    for (int r0 = 0; r0 < 4; ++r0) {
      if ((r0 & m) == 0) {
        const int r1 = r0 | m;
        float a0r = ar[r0], a0i = ai[r0], a1r = ar[r1], a1i = ai[r1];
        ar[r0] = fmaf(-s, a1r, c * a0r);
        ai[r0] = fmaf(-s, a1i, c * a0i);
        ar[r1] = fmaf(s, a0r, c * a1r);
        ai[r1] = fmaf(s, a0i, c * a1i);
      }
    }
  }
}

__device__ __forceinline__ void rx_gate(float* ar, float* ai, int lane, int q,
                                        float c, float s) {
  // M = [[c, -i s], [-i s, c]] : new = c*mine + (-i s)*partner (symmetric)
  const int p = 7 - q;
  if (p >= 2) {
    const int lm = 1 << (p - 2);
#pragma unroll
    for (int r = 0; r < 4; ++r) {
      float pr = __shfl_xor(ar[r], lm, 64);
      float pi = __shfl_xor(ai[r], lm, 64);
      ar[r] = fmaf(s, pi, c * ar[r]);
      ai[r] = fmaf(-s, pr, c * ai[r]);
    }
  } else {
    const int m = 1 << p;
#pragma unroll
    for (int r0 = 0; r0 < 4; ++r0) {
      if ((r0 & m) == 0) {
        const int r1 = r0 | m;
        float a0r = ar[r0], a0i = ai[r0], a1r = ar[r1], a1i = ai[r1];
        ar[r0] = fmaf(s, a1i, c * a0r);
        ai[r0] = fmaf(-s, a1r, c * a0i);
        ar[r1] = fmaf(s, a0i, c * a1r);
        ai[r1] = fmaf(-s, a0r, c * a1i);
      }
    }
  }
}

__device__ __forceinline__ void rz_gate(float* ar, float* ai, int lane, int q,
                                        float c, float s) {
  // diag(e^{-i t/2}, e^{+i t/2}); bit0: (c,-s), bit1: (c,+s). No shuffles.
  const int p = 7 - q;
  if (p >= 2) {
    const float d = ((lane >> (p - 2)) & 1) ? s : -s;
#pragma unroll
    for (int r = 0; r < 4; ++r) {
      float mr = ar[r], mi = ai[r];
      ar[r] = fmaf(-d, mi, c * mr);
      ai[r] = fmaf(d, mr, c * mi);
    }
  } else {
#pragma unroll
    for (int r = 0; r < 4; ++r) {
      const float d = ((r >> p) & 1) ? s : -s;
      float mr = ar[r], mi = ai[r];
      ar[r] = fmaf(-d, mi, c * mr);
      ai[r] = fmaf(d, mr, c * mi);
    }
  }
}

__device__ __forceinline__ void cry_gate(float* ar, float* ai, int lane, int cw, int tw,
                                         float cc, float sc) {
  const int pc = 7 - cw, pt = 7 - tw;  // cw < tw  =>  pc > pt
  if (pt >= 2) {
    const int lm = 1 << (pt - 2);
    const bool ctrl = (lane >> (pc - 2)) & 1;  // pc > pt >= 2: lane bit
    const float sg = ((lane >> (pt - 2)) & 1) ? sc : -sc;
#pragma unroll
    for (int r = 0; r < 4; ++r) {
      float pr = __shfl_xor(ar[r], lm, 64);
      float pi = __shfl_xor(ai[r], lm, 64);
      float nr = fmaf(sg, pr, cc * ar[r]);
      float ni = fmaf(sg, pi, cc * ai[r]);
      ar[r] = ctrl ? nr : ar[r];
      ai[r] = ctrl ? ni : ai[r];
    }
  } else {
    const int m = 1 << pt;
#pragma unroll
    for (int r0 = 0; r0 < 4; ++r0) {
      if ((r0 & m) == 0) {
        const int r1 = r0 | m;
        const bool ctrl = (pc >= 2) ? ((lane >> (pc - 2)) & 1) : ((r0 >> pc) & 1);
        float a0r = ar[r0], a0i = ai[r0], a1r = ar[r1], a1i = ai[r1];
        float n0r = fmaf(-sc, a1r, cc * a0r);
        float n0i = fmaf(-sc, a1i, cc * a0i);
        float n1r = fmaf(sc, a0r, cc * a1r);
        float n1i = fmaf(sc, a0i, cc * a1i);
        ar[r0] = ctrl ? n0r : a0r;  ai[r0] = ctrl ? n0i : a0i;
        ar[r1] = ctrl ? n1r : a1r;  ai[r1] = ctrl ? n1i : a1i;
      }
    }
  }
}

__device__ __forceinline__ void crx_gate(float* ar, float* ai, int lane, int cw, int tw,
                                         float cc, float sc) {
  const int pc = 7 - cw, pt = 7 - tw;
  if (pt >= 2) {
    const int lm = 1 << (pt - 2);
    const bool ctrl = (lane >> (pc - 2)) & 1;
#pragma unroll
    for (int r = 0; r < 4; ++r) {
      float pr = __shfl_xor(ar[r], lm, 64);
      float pi = __shfl_xor(ai[r], lm, 64);
      float nr = fmaf(sc, pi, cc * ar[r]);
      float ni = fmaf(-sc, pr, cc * ai[r]);
      ar[r] = ctrl ? nr : ar[r];
      ai[r] = ctrl ? ni : ai[r];
    }
  } else {
    const int m = 1 << pt;
#pragma unroll
    for (int r0 = 0; r0 < 4; ++r0) {
      if ((r0 & m) == 0) {
        const int r1 = r0 | m;
        const bool ctrl = (pc >= 2) ? ((lane >> (pc - 2)) & 1) : ((r0 >> pc) & 1);
        float a0r = ar[r0], a0i = ai[r0], a1r = ar[r1], a1i = ai[r1];
        float n0r = fmaf(sc, a1i, cc * a0r);
        float n0i = fmaf(-sc, a1r, cc * a0i);
        float n1r = fmaf(sc, a0i, cc * a1r);
        float n1i = fmaf(-sc, a0r, cc * a1i);
        ar[r0] = ctrl ? n0r : a0r;  ai[r0] = ctrl ? n0i : a0i;
        ar[r1] = ctrl ? n1r : a1r;  ai[r1] = ctrl ? n1i : a1i;
      }
    }
  }
}

__device__ __forceinline__ void crz_gate(float* ar, float* ai, int lane, int cw, int tw,
                                         float cc, float sc) {
  const int pc = 7 - cw, pt = 7 - tw;  // diagonal: no shuffles
#pragma unroll
  for (int r = 0; r < 4; ++r) {
    const bool ctrl = (pc >= 2) ? ((lane >> (pc - 2)) & 1) : ((r >> pc) & 1);
    const bool bt   = (pt >= 2) ? ((lane >> (pt - 2)) & 1) : ((r >> pt) & 1);
    const float d = bt ? sc : -sc;
    float mr = ar[r], mi = ai[r];
    float nr = fmaf(-d, mi, cc * mr);
    float ni = fmaf(d, mr, cc * mi);
    ar[r] = ctrl ? nr : mr;
    ai[r] = ctrl ? ni : mi;
  }
}

} // namespace

__global__ __launch_bounds__(256) void qugcn_sim(const float* __restrict__ x,
                                                 const float* __restrict__ qw,
                                                 const float* __restrict__ fcw,
                                                 const float* __restrict__ fcb,
                                                 float* __restrict__ out) {
  const int lane = threadIdx.x & 63;
  const int wid  = threadIdx.x >> 6;
  const int b    = blockIdx.x * 4 + wid;   // sample (column of x), 0..4095

  // ---- load column b of x; amplitude s = (lane<<2)|r ----
  float ar[4], ai[4];
#pragma unroll
  for (int r = 0; r < 4; ++r) {
    const int s = (lane << 2) | r;
    ar[r] = x[(size_t)s * NSAMP + b];
    ai[r] = 0.f;
  }
  // ---- L2 normalize (AmplitudeEmbedding, normalize=True) ----
  float ss = ar[0]*ar[0] + ar[1]*ar[1] + ar[2]*ar[2] + ar[3]*ar[3];
#pragma unroll
  for (int off = 32; off; off >>= 1) ss += __shfl_xor(ss, off, 64);
  const float rn = 1.0f / sqrtf(ss);
#pragma unroll
  for (int r = 0; r < 4; ++r) ar[r] *= rn;

  // ---- 4 layers x 132 gates ----
  for (int L = 0; L < LAYERS; ++L) {
    const float* wv = qw + L * NW_L;

    // RY wv[0..7]
#pragma unroll
    for (int q = 0; q < 8; ++q) {
      const float t = 0.5f * wv[q];
      ry_gate(ar, ai, lane, q, __cosf(t), __sinf(t));
    }
    // CRY constants (angles 8..35)
#pragma unroll
    for (int i = 0; i < 28; ++i)
      cry_gate(ar, ai, lane, PC[i], PT[i], T_CRY.c[i], T_CRY.s[i]);
    // RY wv[36..43]
#pragma unroll
    for (int q = 0; q < 8; ++q) {
      const float t = 0.5f * wv[36 + q];
      ry_gate(ar, ai, lane, q, __cosf(t), __sinf(t));
    }
    // RX wv[44..51]
#pragma unroll
    for (int q = 0; q < 8; ++q) {
      const float t = 0.5f * wv[44 + q];
      rx_gate(ar, ai, lane, q, __cosf(t), __sinf(t));
    }
    // CRX constants (angles 52..79)
#pragma unroll
    for (int i = 0; i < 28; ++i)
      crx_gate(ar, ai, lane, PC[i], PT[i], T_CRX.c[i], T_CRX.s[i]);
    // RX wv[80..87]
#pragma unroll
    for (int q = 0; q < 8; ++q) {
      const float t = 0.5f * wv[80 + q];
      rx_gate(ar, ai, lane, q, __cosf(t), __sinf(t));
    }
    // RZ wv[88..95]
#pragma unroll
    for (int q = 0; q < 8; ++q) {
      const float t = 0.5f * wv[88 + q];
      rz_gate(ar, ai, lane, q, __cosf(t), __sinf(t));
    }
    // CRZ constants (angles 96..123)
#pragma unroll
    for (int i = 0; i < 28; ++i)
      crz_gate(ar, ai, lane, PC[i], PT[i], T_CRZ.c[i], T_CRZ.s[i]);
    // RZ wv[124..131]
#pragma unroll
    for (int q = 0; q < 8; ++q) {
      const float t = 0.5f * wv[124 + q];
      rz_gate(ar, ai, lane, q, __cosf(t), __sinf(t));
    }
  }

  // ---- probabilities and <Z_q> ----
  float p4[4];
#pragma unroll
  for (int r = 0; r < 4; ++r) p4[r] = ar[r]*ar[r] + ai[r]*ai[r];

  float z[8];
#pragma unroll
  for (int q = 0; q < 8; ++q) {
    const int pbit = 7 - q;
    float acc = 0.f;
#pragma unroll
    for (int r = 0; r < 4; ++r) {
      const int bit = (pbit >= 2) ? ((lane >> (pbit - 2)) & 1) : ((r >> pbit) & 1);
      acc += bit ? -p4[r] : p4[r];
    }
#pragma unroll
    for (int off = 32; off; off >>= 1) acc += __shfl_xor(acc, off, 64);
    z[q] = acc;
  }

  // ---- linear head: out[b, o] = fc_b[o] + sum_q fc_w[o,q] * z[q] ----
  if (lane < 7) {
    float o = fcb[lane];
#pragma unroll
    for (int q = 0; q < 8; ++q) o = fmaf(fcw[lane * 8 + q], z[q], o);
    out[(size_t)b * 7 + lane] = o;
  }
}

extern "C" void kernel_launch(void* const* d_in, const int* in_sizes, int n_in,
                              void* d_out, int out_size, void* d_ws, size_t ws_size,
                              hipStream_t stream) {
  const float* x   = (const float*)d_in[0];   // [256, 4096]
  const float* qw  = (const float*)d_in[1];   // [4, 132]
  const float* fcw = (const float*)d_in[2];   // [7, 8]
  const float* fcb = (const float*)d_in[3];   // [7]
  float* out = (float*)d_out;                 // [4096, 7]
  hipLaunchKernelGGL(qugcn_sim, dim3(NSAMP / 4), dim3(256), 0, stream,
                     x, qw, fcw, fcb, out);
}